// Round 1
// 723.016 us; speedup vs baseline: 1.0319x; 1.0319x over previous
//
#include <hip/hip_runtime.h>

typedef __bf16 bf16x8 __attribute__((ext_vector_type(8)));
typedef float floatx4 __attribute__((ext_vector_type(4)));
typedef unsigned short ushort8 __attribute__((ext_vector_type(8)));
typedef unsigned short ushort4v __attribute__((ext_vector_type(4)));

#define MFMA(a, b, c) __builtin_amdgcn_mfma_f32_16x16x32_bf16((a), (b), (c), 0, 0, 0)

__device__ __forceinline__ unsigned short f2bf(float x) {
  union { float f; unsigned u; } v; v.f = x;
  unsigned r = v.u + 0x7FFFu + ((v.u >> 16) & 1u);  // RNE; inputs finite
  return (unsigned short)(r >> 16);
}

constexpr int LD = 72;  // padded row stride (bf16 elems): 144 B, 16B-aligned

__global__ __launch_bounds__(256, 4)
void attn_fwd(const float* __restrict__ Q, const float* __restrict__ K,
              const float* __restrict__ V, float* __restrict__ outQV,
              float* __restrict__ outA)
{
  __shared__ __align__(16) unsigned short Ks[64 * LD];
  __shared__ __align__(16) unsigned short Vts[64 * LD];  // Vts[d][m]
  __shared__ __align__(16) unsigned short As[64 * LD];   // P staging, wave-private rows

  const int tid = threadIdx.x;
  const int w  = tid >> 6;   // wave 0..3 -> q rows [16w,16w+16)
  const int l  = tid & 63;
  const int c  = l & 15;
  const int q4 = l >> 4;

  const int bx = blockIdx.x;
  const int qt = bx & 31;
  const int h  = (bx >> 5) & 7;
  const int b  = bx >> 8;
  const int q0 = qt * 64;

  const float scale = 0.125f * 1.44269504088896340736f;  // 1/sqrt(64) * log2(e)

  const size_t base = (size_t)b * (2048 * 512) + (size_t)h * 64;  // + n*512 + d
  const float* Qb = Q + base + (size_t)q0 * 512;
  const float* Kb = K + base;
  const float* Vb = V + base;

  const int r0 = tid >> 4;   // loader row
  const int c4 = tid & 15;   // loader float4 column

  // ---- Q fragments straight to registers (B-operand of swapped QK^T) ----
  // lane (c,q4) holds Q[16w+c][q4*8 .. +7] and Q[16w+c][32+q4*8 .. +7], scaled.
  bf16x8 bQ0, bQ1;
  {
    const float* qp = Qb + (size_t)(16 * w + c) * 512 + q4 * 8;
    float4 qa0 = *(const float4*)(qp);
    float4 qa1 = *(const float4*)(qp + 4);
    float4 qb0 = *(const float4*)(qp + 32);
    float4 qb1 = *(const float4*)(qp + 36);
    ushort8 t0, t1;
    t0[0]=f2bf(qa0.x*scale); t0[1]=f2bf(qa0.y*scale); t0[2]=f2bf(qa0.z*scale); t0[3]=f2bf(qa0.w*scale);
    t0[4]=f2bf(qa1.x*scale); t0[5]=f2bf(qa1.y*scale); t0[6]=f2bf(qa1.z*scale); t0[7]=f2bf(qa1.w*scale);
    t1[0]=f2bf(qb0.x*scale); t1[1]=f2bf(qb0.y*scale); t1[2]=f2bf(qb0.z*scale); t1[3]=f2bf(qb0.w*scale);
    t1[4]=f2bf(qb1.x*scale); t1[5]=f2bf(qb1.y*scale); t1[6]=f2bf(qb1.z*scale); t1[7]=f2bf(qb1.w*scale);
    bQ0 = __builtin_bit_cast(bf16x8, t0);
    bQ1 = __builtin_bit_cast(bf16x8, t1);
  }

  // ---- pass 1: per-row sum of exp2(S) (no max-sub; |s2| < ~12, fp32-safe) ----
  // prefetch K tile 0 into registers (T14: issue-early / write-late)
  float4 kreg[4];
  #pragma unroll
  for (int g = 0; g < 4; ++g)
    kreg[g] = *(const float4*)(Kb + (size_t)(r0 + 16 * g) * 512 + c4 * 4);

  float lsum[4] = {0.f, 0.f, 0.f, 0.f};
  for (int mc = 0; mc < 2048; mc += 64) {
    // write-late: convert prefetched regs -> LDS (prev compute finished at loop-end barrier)
    #pragma unroll
    for (int g = 0; g < 4; ++g) {
      unsigned short* dst = &Ks[(r0 + 16 * g) * LD + c4 * 4];
      dst[0] = f2bf(kreg[g].x); dst[1] = f2bf(kreg[g].y);
      dst[2] = f2bf(kreg[g].z); dst[3] = f2bf(kreg[g].w);
    }
    __syncthreads();
    // issue-early: next tile's loads fly during compute
    if (mc + 64 < 2048) {
      #pragma unroll
      for (int g = 0; g < 4; ++g)
        kreg[g] = *(const float4*)(Kb + (size_t)(mc + 64 + r0 + 16 * g) * 512 + c4 * 4);
    }
    #pragma unroll
    for (int t = 0; t < 4; ++t) {
      bf16x8 aK0 = *(const bf16x8*)&Ks[(t * 16 + c) * LD + q4 * 8];
      bf16x8 aK1 = *(const bf16x8*)&Ks[(t * 16 + c) * LD + 32 + q4 * 8];
      floatx4 acc = {0.f, 0.f, 0.f, 0.f};
      acc = MFMA(aK0, bQ0, acc);   // swapped: S^T tile -> lane holds S[q=16w+c][m=t*16+q4*4+i]
      acc = MFMA(aK1, bQ1, acc);
      #pragma unroll
      for (int i = 0; i < 4; ++i) lsum[i] += __builtin_amdgcn_exp2f(acc[i]);
    }
    __syncthreads();
  }
  // each lane owns one q-row (16w+c); q4 groups hold disjoint m-subsets -> reduce over q4
  float rs = (lsum[0] + lsum[1]) + (lsum[2] + lsum[3]);
  rs += __shfl_xor(rs, 16);
  rs += __shfl_xor(rs, 32);
  const float rcp = 1.0f / rs;

  // ---- pass 2: recompute S, write A (float4 nt stores), accumulate O = A*V ----
  floatx4 Oacc[4];
  #pragma unroll
  for (int t = 0; t < 4; ++t) Oacc[t] = (floatx4){0.f, 0.f, 0.f, 0.f};

  float* aRowP = outA + (((size_t)(b * 8 + h) * 2048 + q0 + 16 * w + c) * 2048) + q4 * 4;

  // prefetch K,V tile 0
  float4 vreg[4];
  #pragma unroll
  for (int g = 0; g < 4; ++g) {
    kreg[g] = *(const float4*)(Kb + (size_t)(r0 + 16 * g) * 512 + c4 * 4);
    vreg[g] = *(const float4*)(Vb + (size_t)(r0 + 16 * g) * 512 + c4 * 4);
  }

  for (int mc = 0; mc < 2048; mc += 64) {
    // write-late staging from regs (prev-iter compute done at loop-end barrier)
    #pragma unroll
    for (int g = 0; g < 4; ++g) {
      unsigned short* dst = &Ks[(r0 + 16 * g) * LD + c4 * 4];
      dst[0] = f2bf(kreg[g].x); dst[1] = f2bf(kreg[g].y);
      dst[2] = f2bf(kreg[g].z); dst[3] = f2bf(kreg[g].w);
      int m = r0 + 16 * g;
      Vts[(c4 * 4 + 0) * LD + m] = f2bf(vreg[g].x);
      Vts[(c4 * 4 + 1) * LD + m] = f2bf(vreg[g].y);
      Vts[(c4 * 4 + 2) * LD + m] = f2bf(vreg[g].z);
      Vts[(c4 * 4 + 3) * LD + m] = f2bf(vreg[g].w);
    }
    __syncthreads();
    // issue-early next tile
    if (mc + 64 < 2048) {
      #pragma unroll
      for (int g = 0; g < 4; ++g) {
        kreg[g] = *(const float4*)(Kb + (size_t)(mc + 64 + r0 + 16 * g) * 512 + c4 * 4);
        vreg[g] = *(const float4*)(Vb + (size_t)(mc + 64 + r0 + 16 * g) * 512 + c4 * 4);
      }
    }
    #pragma unroll
    for (int t = 0; t < 4; ++t) {
      bf16x8 aK0 = *(const bf16x8*)&Ks[(t * 16 + c) * LD + q4 * 8];
      bf16x8 aK1 = *(const bf16x8*)&Ks[(t * 16 + c) * LD + 32 + q4 * 8];
      floatx4 acc = {0.f, 0.f, 0.f, 0.f};
      acc = MFMA(aK0, bQ0, acc);
      acc = MFMA(aK1, bQ1, acc);
      // lane (c,q4): A[q=16w+c][mc + t*16 + q4*4 .. +3]  -> 16B/lane, 64B/row segments
      floatx4 av;
      av[0] = __builtin_amdgcn_exp2f(acc[0]) * rcp;
      av[1] = __builtin_amdgcn_exp2f(acc[1]) * rcp;
      av[2] = __builtin_amdgcn_exp2f(acc[2]) * rcp;
      av[3] = __builtin_amdgcn_exp2f(acc[3]) * rcp;
      __builtin_nontemporal_store(av, (floatx4*)(aRowP + mc + t * 16));
      ushort4v us = { f2bf(av[0]), f2bf(av[1]), f2bf(av[2]), f2bf(av[3]) };
      *(ushort4v*)&As[(16 * w + c) * LD + t * 16 + q4 * 4] = us;  // wave-private rows, b64 write
    }
    // PV: A-operand = P rows (own wave's rows only -> same-wave LDS RAW, no barrier needed)
    bf16x8 aP0 = *(const bf16x8*)&As[(16 * w + c) * LD + q4 * 8];
    bf16x8 aP1 = *(const bf16x8*)&As[(16 * w + c) * LD + 32 + q4 * 8];
    #pragma unroll
    for (int t = 0; t < 4; ++t) {
      bf16x8 bV0 = *(const bf16x8*)&Vts[(t * 16 + c) * LD + q4 * 8];
      bf16x8 bV1 = *(const bf16x8*)&Vts[(t * 16 + c) * LD + 32 + q4 * 8];
      Oacc[t] = MFMA(aP0, bV0, Oacc[t]);
      Oacc[t] = MFMA(aP1, bV1, Oacc[t]);
    }
    __syncthreads();
  }

  // ---- write queried_values [B,N,H,D] ----
  #pragma unroll
  for (int t = 0; t < 4; ++t) {
    #pragma unroll
    for (int i = 0; i < 4; ++i) {
      outQV[base + (size_t)(q0 + 16 * w + q4 * 4 + i) * 512 + t * 16 + c] = Oacc[t][i];
    }
  }
}

extern "C" void kernel_launch(void* const* d_in, const int* in_sizes, int n_in,
                              void* d_out, int out_size, void* d_ws, size_t ws_size,
                              hipStream_t stream)
{
  const float* Q = (const float*)d_in[0];
  const float* K = (const float*)d_in[1];
  const float* V = (const float*)d_in[2];
  float* outQV = (float*)d_out;                 // [4,2048,8,64] = 4194304 floats
  float* outA  = (float*)d_out + 4194304;       // [4,8,2048,2048]
  attn_fwd<<<dim3(1024), dim3(256), 0, stream>>>(Q, K, V, outQV, outA);
}

// Round 2
// 656.202 us; speedup vs baseline: 1.1369x; 1.1018x over previous
//
#include <hip/hip_runtime.h>

typedef __bf16 bf16x8 __attribute__((ext_vector_type(8)));
typedef float floatx4 __attribute__((ext_vector_type(4)));
typedef unsigned short ushort8 __attribute__((ext_vector_type(8)));
typedef unsigned short ushort4v __attribute__((ext_vector_type(4)));

#define MFMA(a, b, c) __builtin_amdgcn_mfma_f32_16x16x32_bf16((a), (b), (c), 0, 0, 0)

__device__ __forceinline__ unsigned short f2bf(float x) {
  union { float f; unsigned u; } v; v.f = x;
  unsigned r = v.u + 0x7FFFu + ((v.u >> 16) & 1u);  // RNE; inputs finite
  return (unsigned short)(r >> 16);
}

// ---------------------------------------------------------------------------
// prep: K -> bf16 tiles, V -> TRANSPOSED bf16 tiles, both pre-swizzled.
// Tile = 64 rows x 128 B (64 bf16). Global chunk g = r*8+s (16 B) holds the
// original bytes [(s ^ (r&7))*16 .. +15] of row r, so a LINEAR
// global_load_lds lands them XOR-swizzled in LDS (rule #21: inverse-swz
// source + swz read; XOR is an involution).
// K tile (b,h,mt): row r = key m = mt*64+r, row axis = d (64 bf16).
// V tile (b,h,mt): row r = d,              row axis = m (64 bf16), i.e. V^T.
// ---------------------------------------------------------------------------
__global__ __launch_bounds__(256)
void prep(const float* __restrict__ K, const float* __restrict__ V,
          unsigned short* __restrict__ Kb, unsigned short* __restrict__ Vt)
{
  int id = blockIdx.x * 256 + threadIdx.x;   // 0 .. 2*524288-1
  int isV = id >> 19;
  int cch = id & 524287;                     // chunk id within K or V half
  int bh = cch >> 14;                        // b*8+h  (32*512 chunks per bh)
  int mt = (cch >> 9) & 31;
  int g  = cch & 511;
  int r  = g >> 3;
  int s  = g & 7;
  int e8 = s ^ (r & 7);                      // 8-elem group along the row axis
  int b = bh >> 3, h = bh & 7;
  ushort8 o;
  if (!isV) {
    // row r = m, elems d = e8*8..+7 : contiguous floats
    const float* p = K + (((size_t)(b * 2048 + mt * 64 + r) * 8 + h) * 64 + e8 * 8);
    float4 x0 = *(const float4*)p;
    float4 x1 = *(const float4*)(p + 4);
    o[0] = f2bf(x0.x); o[1] = f2bf(x0.y); o[2] = f2bf(x0.z); o[3] = f2bf(x0.w);
    o[4] = f2bf(x1.x); o[5] = f2bf(x1.y); o[6] = f2bf(x1.z); o[7] = f2bf(x1.w);
    *(ushort8*)(Kb + (size_t)cch * 8) = o;
  } else {
    // row r = d, elems m = mt*64 + e8*8..+7 : stride 512 floats
    const float* p = V + (((size_t)(b * 2048 + mt * 64 + e8 * 8) * 8 + h) * 64 + r);
    #pragma unroll
    for (int j = 0; j < 8; ++j) o[j] = f2bf(p[(size_t)j * 512]);
    *(ushort8*)(Vt + (size_t)cch * 8) = o;
  }
}

// wave-cooperative stage of one 2 KB slice (wave w) of an 8 KB tile via DMA:
// LDS dest is wave-uniform base + lane*16 (HW rule); global src is per-lane.
__device__ __forceinline__ void stage2k(const unsigned short* gsrc, unsigned short* lds,
                                        int w, int l)
{
  const char* g = (const char*)gsrc + w * 2048 + l * 16;
  char* sd = (char*)lds + w * 2048;
  __builtin_amdgcn_global_load_lds((const __attribute__((address_space(1))) unsigned int*)g,
                                   (__attribute__((address_space(3))) unsigned int*)sd, 16, 0, 0);
  __builtin_amdgcn_global_load_lds((const __attribute__((address_space(1))) unsigned int*)(g + 1024),
                                   (__attribute__((address_space(3))) unsigned int*)(sd + 1024), 16, 0, 0);
}

// swizzled 16B fragment read from a [64][128B] tile; bo = original byte col (16B-mult)
__device__ __forceinline__ bf16x8 frag(const unsigned short* lds, int r, int bo)
{
  int slot = ((bo >> 4) ^ r) & 7;
  return *(const bf16x8*)((const char*)lds + r * 128 + (slot << 4));
}

__global__ __launch_bounds__(256, 4)
void attn_fwd(const float* __restrict__ Q, const unsigned short* __restrict__ Kb,
              const unsigned short* __restrict__ Vt,
              float* __restrict__ outQV, float* __restrict__ outA)
{
  __shared__ __align__(16) unsigned short Ks[2][4096];   // dbuf K tiles (8 KB each)
  __shared__ __align__(16) unsigned short Vs[2][4096];   // dbuf V^T tiles
  __shared__ __align__(16) unsigned short As[4096];      // P staging [64][64], swizzled
  // total 40960 B -> exactly 4 blocks/CU

  const int tid = threadIdx.x;
  const int w  = tid >> 6;   // wave 0..3 -> q rows [16w,16w+16)
  const int l  = tid & 63;
  const int c  = l & 15;
  const int q4 = l >> 4;

  const int bx = blockIdx.x;
  const int qt = bx & 31;
  const int h  = (bx >> 5) & 7;
  const int b  = bx >> 8;
  const int q0 = qt * 64;

  const float scale = 0.125f * 1.44269504088896340736f;  // 1/sqrt(64) * log2(e)

  const size_t base = (size_t)b * (2048 * 512) + (size_t)h * 64;  // + n*512 + d
  const float* Qb = Q + base + (size_t)q0 * 512;

  const unsigned short* Kt0 = Kb + (size_t)(b * 8 + h) * (32 * 4096);
  const unsigned short* Vt0 = Vt + (size_t)(b * 8 + h) * (32 * 4096);

  // ---- Q fragments straight to registers (B-operand of swapped QK^T) ----
  bf16x8 bQ0, bQ1;
  {
    const float* qp = Qb + (size_t)(16 * w + c) * 512 + q4 * 8;
    float4 qa0 = *(const float4*)(qp);
    float4 qa1 = *(const float4*)(qp + 4);
    float4 qb0 = *(const float4*)(qp + 32);
    float4 qb1 = *(const float4*)(qp + 36);
    ushort8 t0, t1;
    t0[0]=f2bf(qa0.x*scale); t0[1]=f2bf(qa0.y*scale); t0[2]=f2bf(qa0.z*scale); t0[3]=f2bf(qa0.w*scale);
    t0[4]=f2bf(qa1.x*scale); t0[5]=f2bf(qa1.y*scale); t0[6]=f2bf(qa1.z*scale); t0[7]=f2bf(qa1.w*scale);
    t1[0]=f2bf(qb0.x*scale); t1[1]=f2bf(qb0.y*scale); t1[2]=f2bf(qb0.z*scale); t1[3]=f2bf(qb0.w*scale);
    t1[4]=f2bf(qb1.x*scale); t1[5]=f2bf(qb1.y*scale); t1[6]=f2bf(qb1.z*scale); t1[7]=f2bf(qb1.w*scale);
    bQ0 = __builtin_bit_cast(bf16x8, t0);
    bQ1 = __builtin_bit_cast(bf16x8, t1);
  }

  // ---- pass 1: per-row sum of exp2(S); K staged by DMA, dbuf, 1 barrier/iter ----
  stage2k(Kt0, Ks[0], w, l);
  float lsum[4] = {0.f, 0.f, 0.f, 0.f};
  int cur = 0;
  for (int mt = 0; mt < 32; ++mt) {
    __syncthreads();  // drains own vmcnt (stage of Ks[cur] complete everywhere)
    if (mt + 1 < 32) stage2k(Kt0 + (size_t)(mt + 1) * 4096, Ks[cur ^ 1], w, l);
    const unsigned short* Kc = Ks[cur];
    #pragma unroll
    for (int t = 0; t < 4; ++t) {
      bf16x8 aK0 = frag(Kc, t * 16 + c, q4 * 16);
      bf16x8 aK1 = frag(Kc, t * 16 + c, 64 + q4 * 16);
      floatx4 acc = {0.f, 0.f, 0.f, 0.f};
      acc = MFMA(aK0, bQ0, acc);   // swapped: lane holds S[q=16w+c][m=t*16+q4*4+i]
      acc = MFMA(aK1, bQ1, acc);
      #pragma unroll
      for (int i = 0; i < 4; ++i) lsum[i] += __builtin_amdgcn_exp2f(acc[i]);
    }
    cur ^= 1;
  }
  // lane owns one q-row (16w+c); q4 groups hold disjoint m-subsets -> reduce over q4
  float rs = (lsum[0] + lsum[1]) + (lsum[2] + lsum[3]);
  rs += __shfl_xor(rs, 16);
  rs += __shfl_xor(rs, 32);
  const float rcp = 1.0f / rs;

  // ---- pass 2: recompute S, write A (nt dwordx4), accumulate O = A*V ----
  floatx4 Oacc[4];
  #pragma unroll
  for (int t = 0; t < 4; ++t) Oacc[t] = (floatx4){0.f, 0.f, 0.f, 0.f};

  const int arow = 16 * w + c;
  float* aRowP = outA + (((size_t)(b * 8 + h) * 2048 + q0 + arow) * 2048) + q4 * 4;

  __syncthreads();                 // pass-1 readers done before re-staging Ks[0]
  stage2k(Kt0, Ks[0], w, l);
  stage2k(Vt0, Vs[0], w, l);
  cur = 0;
  for (int mt = 0; mt < 32; ++mt) {
    __syncthreads();  // stage of buf[cur] complete everywhere; prev buf free
    if (mt + 1 < 32) {
      stage2k(Kt0 + (size_t)(mt + 1) * 4096, Ks[cur ^ 1], w, l);
      stage2k(Vt0 + (size_t)(mt + 1) * 4096, Vs[cur ^ 1], w, l);
    }
    const unsigned short* Kc = Ks[cur];
    const unsigned short* Vc = Vs[cur];
    const int mc = mt * 64;
    #pragma unroll
    for (int t = 0; t < 4; ++t) {
      bf16x8 aK0 = frag(Kc, t * 16 + c, q4 * 16);
      bf16x8 aK1 = frag(Kc, t * 16 + c, 64 + q4 * 16);
      floatx4 acc = {0.f, 0.f, 0.f, 0.f};
      acc = MFMA(aK0, bQ0, acc);
      acc = MFMA(aK1, bQ1, acc);
      floatx4 av;
      av[0] = __builtin_amdgcn_exp2f(acc[0]) * rcp;
      av[1] = __builtin_amdgcn_exp2f(acc[1]) * rcp;
      av[2] = __builtin_amdgcn_exp2f(acc[2]) * rcp;
      av[3] = __builtin_amdgcn_exp2f(acc[3]) * rcp;
      __builtin_nontemporal_store(av, (floatx4*)(aRowP + mc + t * 16));
      // As[arow][t*16 + q4*4 .. +3], 16B-slot XOR swizzle (2-way banks, b64-aligned)
      ushort4v us = { f2bf(av[0]), f2bf(av[1]), f2bf(av[2]), f2bf(av[3]) };
      int bo = t * 32 + q4 * 8;                       // byte col within row
      int slot = ((bo >> 4) ^ arow) & 7;
      *(ushort4v*)((char*)As + arow * 128 + (slot << 4) + (bo & 15)) = us;
    }
    // PV: aP = own wave's P rows (same-wave LDS RAW, compiler waits lgkmcnt)
    bf16x8 aP0 = frag(As, arow, q4 * 16);
    bf16x8 aP1 = frag(As, arow, 64 + q4 * 16);
    #pragma unroll
    for (int t = 0; t < 4; ++t) {
      bf16x8 bV0 = frag(Vc, t * 16 + c, q4 * 16);
      bf16x8 bV1 = frag(Vc, t * 16 + c, 64 + q4 * 16);
      Oacc[t] = MFMA(aP0, bV0, Oacc[t]);
      Oacc[t] = MFMA(aP1, bV1, Oacc[t]);
    }
    cur ^= 1;
  }

  // ---- write queried_values [B,N,H,D] ----
  #pragma unroll
  for (int t = 0; t < 4; ++t) {
    #pragma unroll
    for (int i = 0; i < 4; ++i) {
      outQV[base + (size_t)(q0 + 16 * w + q4 * 4 + i) * 512 + t * 16 + c] = Oacc[t][i];
    }
  }
}

extern "C" void kernel_launch(void* const* d_in, const int* in_sizes, int n_in,
                              void* d_out, int out_size, void* d_ws, size_t ws_size,
                              hipStream_t stream)
{
  const float* Q = (const float*)d_in[0];
  const float* K = (const float*)d_in[1];
  const float* V = (const float*)d_in[2];
  float* outQV = (float*)d_out;                 // [4,2048,8,64] = 4194304 floats
  float* outA  = (float*)d_out + 4194304;       // [4,8,2048,2048]

  unsigned short* Kb = (unsigned short*)d_ws;           // 8 MB swizzled bf16 K tiles
  unsigned short* Vt = (unsigned short*)d_ws + 4194304; // 8 MB swizzled bf16 V^T tiles

  prep<<<dim3(4096), dim3(256), 0, stream>>>(K, V, Kb, Vt);
  attn_fwd<<<dim3(1024), dim3(256), 0, stream>>>(Q, Kb, Vt, outQV, outA);
}

// Round 3
// 634.042 us; speedup vs baseline: 1.1767x; 1.0350x over previous
//
#include <hip/hip_runtime.h>

typedef __bf16 bf16x8 __attribute__((ext_vector_type(8)));
typedef float floatx4 __attribute__((ext_vector_type(4)));
typedef unsigned short ushort8 __attribute__((ext_vector_type(8)));
typedef unsigned short ushort4v __attribute__((ext_vector_type(4)));

#define MFMA(a, b, c) __builtin_amdgcn_mfma_f32_16x16x32_bf16((a), (b), (c), 0, 0, 0)

__device__ __forceinline__ unsigned short f2bf(float x) {
  union { float f; unsigned u; } v; v.f = x;
  unsigned r = v.u + 0x7FFFu + ((v.u >> 16) & 1u);  // RNE; inputs finite
  return (unsigned short)(r >> 16);
}

// ---------------------------------------------------------------------------
// prep: K -> bf16 tiles, V -> TRANSPOSED bf16 tiles, both pre-swizzled.
// Tile = 64 rows x 128 B (64 bf16). Global chunk g = r*8+s (16 B) holds the
// original bytes [(s ^ (r&7))*16 .. +15] of row r, so a LINEAR
// global_load_lds lands them XOR-swizzled in LDS (rule #21 involution).
// K tile (b,h,mt): row r = key m = mt*64+r, row axis = d (64 bf16).
// V tile (b,h,mt): row r = d,              row axis = m (64 bf16), i.e. V^T.
// ---------------------------------------------------------------------------
__global__ __launch_bounds__(256)
void prep(const float* __restrict__ K, const float* __restrict__ V,
          unsigned short* __restrict__ Kb, unsigned short* __restrict__ Vt)
{
  int id = blockIdx.x * 256 + threadIdx.x;   // 0 .. 2*524288-1
  int isV = id >> 19;
  int cch = id & 524287;                     // chunk id within K or V half
  int bh = cch >> 14;                        // b*8+h  (32*512 chunks per bh)
  int mt = (cch >> 9) & 31;
  int g  = cch & 511;
  int r  = g >> 3;
  int s  = g & 7;
  int e8 = s ^ (r & 7);                      // 8-elem group along the row axis
  int b = bh >> 3, h = bh & 7;
  ushort8 o;
  if (!isV) {
    const float* p = K + (((size_t)(b * 2048 + mt * 64 + r) * 8 + h) * 64 + e8 * 8);
    float4 x0 = *(const float4*)p;
    float4 x1 = *(const float4*)(p + 4);
    o[0] = f2bf(x0.x); o[1] = f2bf(x0.y); o[2] = f2bf(x0.z); o[3] = f2bf(x0.w);
    o[4] = f2bf(x1.x); o[5] = f2bf(x1.y); o[6] = f2bf(x1.z); o[7] = f2bf(x1.w);
    *(ushort8*)(Kb + (size_t)cch * 8) = o;
  } else {
    const float* p = V + (((size_t)(b * 2048 + mt * 64 + e8 * 8) * 8 + h) * 64 + r);
    #pragma unroll
    for (int j = 0; j < 8; ++j) o[j] = f2bf(p[(size_t)j * 512]);
    *(ushort8*)(Vt + (size_t)cch * 8) = o;
  }
}

// wave-cooperative stage of one 2 KB slice (wave w) of an 8 KB tile via DMA (2 vmem ops)
__device__ __forceinline__ void stage2k(const unsigned short* gsrc, unsigned short* lds,
                                        int w, int l)
{
  const char* g = (const char*)gsrc + w * 2048 + l * 16;
  char* sd = (char*)lds + w * 2048;
  __builtin_amdgcn_global_load_lds((const __attribute__((address_space(1))) unsigned int*)g,
                                   (__attribute__((address_space(3))) unsigned int*)sd, 16, 0, 0);
  __builtin_amdgcn_global_load_lds((const __attribute__((address_space(1))) unsigned int*)(g + 1024),
                                   (__attribute__((address_space(3))) unsigned int*)(sd + 1024), 16, 0, 0);
}

// swizzled 16B fragment read from a [64][128B] tile; bo = original byte col (16B-mult)
__device__ __forceinline__ bf16x8 frag(const unsigned short* lds, int r, int bo)
{
  int slot = ((bo >> 4) ^ r) & 7;
  return *(const bf16x8*)((const char*)lds + r * 128 + (slot << 4));
}

__global__ __launch_bounds__(256, 4)
void attn_fwd(const float* __restrict__ Q, const unsigned short* __restrict__ Kb,
              const unsigned short* __restrict__ Vt,
              float* __restrict__ outQV, float* __restrict__ outA)
{
  __shared__ __align__(16) unsigned short Ks[2][4096];   // dbuf K tiles (8 KB each)
  __shared__ __align__(16) unsigned short Vs[2][4096];   // dbuf V^T tiles
  __shared__ __align__(16) unsigned short As[4096];      // P staging [64][64], swizzled
  // total 40960 B -> 4 blocks/CU

  const int tid = threadIdx.x;
  const int w  = tid >> 6;   // wave 0..3 -> q rows [16w,16w+16)
  const int l  = tid & 63;
  const int c  = l & 15;
  const int q4 = l >> 4;

  // bijective XCD chunk swizzle: grid 1024 = 8 XCDs x 128; XCD k owns 4 whole (b,h)
  const int bx = (blockIdx.x & 7) * 128 + (blockIdx.x >> 3);
  const int qt = bx & 31;
  const int h  = (bx >> 5) & 7;
  const int b  = bx >> 8;
  const int q0 = qt * 64;

  const float scale = 0.125f * 1.44269504088896340736f;  // 1/sqrt(64) * log2(e)

  const size_t base = (size_t)b * (2048 * 512) + (size_t)h * 64;  // + n*512 + d
  const float* Qb = Q + base + (size_t)q0 * 512;

  const unsigned short* Kt0 = Kb + (size_t)(b * 8 + h) * (32 * 4096);
  const unsigned short* Vt0 = Vt + (size_t)(b * 8 + h) * (32 * 4096);

  // ---- Q fragments straight to registers (B-operand of swapped QK^T) ----
  bf16x8 bQ0, bQ1;
  {
    const float* qp = Qb + (size_t)(16 * w + c) * 512 + q4 * 8;
    float4 qa0 = *(const float4*)(qp);
    float4 qa1 = *(const float4*)(qp + 4);
    float4 qb0 = *(const float4*)(qp + 32);
    float4 qb1 = *(const float4*)(qp + 36);
    ushort8 t0, t1;
    t0[0]=f2bf(qa0.x*scale); t0[1]=f2bf(qa0.y*scale); t0[2]=f2bf(qa0.z*scale); t0[3]=f2bf(qa0.w*scale);
    t0[4]=f2bf(qa1.x*scale); t0[5]=f2bf(qa1.y*scale); t0[6]=f2bf(qa1.z*scale); t0[7]=f2bf(qa1.w*scale);
    t1[0]=f2bf(qb0.x*scale); t1[1]=f2bf(qb0.y*scale); t1[2]=f2bf(qb0.z*scale); t1[3]=f2bf(qb0.w*scale);
    t1[4]=f2bf(qb1.x*scale); t1[5]=f2bf(qb1.y*scale); t1[6]=f2bf(qb1.z*scale); t1[7]=f2bf(qb1.w*scale);
    bQ0 = __builtin_bit_cast(bf16x8, t0);
    bQ1 = __builtin_bit_cast(bf16x8, t1);
  }

  // ---- pass 1: per-row sum of exp2(S); K staged by DMA, dbuf, 1 barrier/iter ----
  stage2k(Kt0, Ks[0], w, l);
  float lsum[4] = {0.f, 0.f, 0.f, 0.f};
  int cur = 0;
  for (int mt = 0; mt < 32; ++mt) {
    __syncthreads();  // stage(mt) complete everywhere (drains own vmcnt)
    if (mt + 1 < 32) stage2k(Kt0 + (size_t)(mt + 1) * 4096, Ks[cur ^ 1], w, l);
    const unsigned short* Kc = Ks[cur];
    __builtin_amdgcn_s_setprio(1);
    #pragma unroll
    for (int t = 0; t < 4; ++t) {
      bf16x8 aK0 = frag(Kc, t * 16 + c, q4 * 16);
      bf16x8 aK1 = frag(Kc, t * 16 + c, 64 + q4 * 16);
      floatx4 acc = {0.f, 0.f, 0.f, 0.f};
      acc = MFMA(aK0, bQ0, acc);   // swapped: lane holds S[q=16w+c][m=t*16+q4*4+i]
      acc = MFMA(aK1, bQ1, acc);
      #pragma unroll
      for (int i = 0; i < 4; ++i) lsum[i] += __builtin_amdgcn_exp2f(acc[i]);
    }
    __builtin_amdgcn_s_setprio(0);
    cur ^= 1;
  }
  float rs = (lsum[0] + lsum[1]) + (lsum[2] + lsum[3]);
  rs += __shfl_xor(rs, 16);
  rs += __shfl_xor(rs, 32);
  const float rcp = 1.0f / rs;

  // ---- pass 2: recompute S, write A, accumulate O = A*V ----
  floatx4 Oacc[4];
  #pragma unroll
  for (int t = 0; t < 4; ++t) Oacc[t] = (floatx4){0.f, 0.f, 0.f, 0.f};

  const int arow = 16 * w + c;
  float* aRowP = outA + (((size_t)(b * 8 + h) * 2048 + q0 + arow) * 2048) + q4 * 4;

  __syncthreads();                 // pass-1 readers done before re-staging Ks[0]
  stage2k(Kt0, Ks[0], w, l);
  stage2k(Vt0, Vs[0], w, l);
  asm volatile("s_waitcnt vmcnt(0)" ::: "memory");   // own stage(0) done
  __builtin_amdgcn_s_barrier();                      // everyone's stage(0) done
  __builtin_amdgcn_sched_barrier(0);
  cur = 0;
  for (int mt = 0; mt < 32; ++mt) {
    if (mt + 1 < 32) {
      stage2k(Kt0 + (size_t)(mt + 1) * 4096, Ks[cur ^ 1], w, l);
      stage2k(Vt0 + (size_t)(mt + 1) * 4096, Vs[cur ^ 1], w, l);
    }
    const unsigned short* Kc = Ks[cur];
    const unsigned short* Vc = Vs[cur];
    const int mc = mt * 64;
    __builtin_amdgcn_s_setprio(1);
    #pragma unroll
    for (int t = 0; t < 4; ++t) {
      bf16x8 aK0 = frag(Kc, t * 16 + c, q4 * 16);
      bf16x8 aK1 = frag(Kc, t * 16 + c, 64 + q4 * 16);
      floatx4 acc = {0.f, 0.f, 0.f, 0.f};
      acc = MFMA(aK0, bQ0, acc);
      acc = MFMA(aK1, bQ1, acc);
      floatx4 av;
      av[0] = __builtin_amdgcn_exp2f(acc[0]) * rcp;
      av[1] = __builtin_amdgcn_exp2f(acc[1]) * rcp;
      av[2] = __builtin_amdgcn_exp2f(acc[2]) * rcp;
      av[3] = __builtin_amdgcn_exp2f(acc[3]) * rcp;
      // plain (cached) store: L2 write-combines the two 64B half-lines per 128B line
      *(floatx4*)(aRowP + mc + t * 16) = av;
      // As[arow][t*16 + q4*4 .. +3], 16B-slot XOR swizzle
      ushort4v us = { f2bf(av[0]), f2bf(av[1]), f2bf(av[2]), f2bf(av[3]) };
      int bo = t * 32 + q4 * 8;                       // byte col within row
      int slot = ((bo >> 4) ^ arow) & 7;
      *(ushort4v*)((char*)As + arow * 128 + (slot << 4) + (bo & 15)) = us;
    }
    // PV: aP = own wave's P rows (same-wave LDS RAW; DS pipe is in-order per wave)
    bf16x8 aP0 = frag(As, arow, q4 * 16);
    bf16x8 aP1 = frag(As, arow, 64 + q4 * 16);
    #pragma unroll
    for (int t = 0; t < 4; ++t) {
      bf16x8 bV0 = frag(Vc, t * 16 + c, q4 * 16);
      bf16x8 bV1 = frag(Vc, t * 16 + c, 64 + q4 * 16);
      Oacc[t] = MFMA(aP0, bV0, Oacc[t]);
      Oacc[t] = MFMA(aP1, bV1, Oacc[t]);
    }
    __builtin_amdgcn_s_setprio(0);
    // T4: counted wait — stage(mt+1) (4 ops) must land; this iter's 4 A-stores may fly
    __builtin_amdgcn_sched_barrier(0);
    asm volatile("s_waitcnt vmcnt(4)" ::: "memory");
    __builtin_amdgcn_s_barrier();
    __builtin_amdgcn_sched_barrier(0);
    cur ^= 1;
  }

  // ---- write queried_values [B,N,H,D] ----
  #pragma unroll
  for (int t = 0; t < 4; ++t) {
    #pragma unroll
    for (int i = 0; i < 4; ++i) {
      outQV[base + (size_t)(q0 + 16 * w + q4 * 4 + i) * 512 + t * 16 + c] = Oacc[t][i];
    }
  }
}

extern "C" void kernel_launch(void* const* d_in, const int* in_sizes, int n_in,
                              void* d_out, int out_size, void* d_ws, size_t ws_size,
                              hipStream_t stream)
{
  const float* Q = (const float*)d_in[0];
  const float* K = (const float*)d_in[1];
  const float* V = (const float*)d_in[2];
  float* outQV = (float*)d_out;                 // [4,2048,8,64] = 4194304 floats
  float* outA  = (float*)d_out + 4194304;       // [4,8,2048,2048]

  unsigned short* Kb = (unsigned short*)d_ws;           // 8 MB swizzled bf16 K tiles
  unsigned short* Vt = (unsigned short*)d_ws + 4194304; // 8 MB swizzled bf16 V^T tiles

  prep<<<dim3(4096), dim3(256), 0, stream>>>(K, V, Kb, Vt);
  attn_fwd<<<dim3(1024), dim3(256), 0, stream>>>(Q, Kb, Vt, outQV, outA);
}